// Round 6
// baseline (158.163 us; speedup 1.0000x reference)
//
#include <hip/hip_runtime.h>
#include <cstdint>
#include <cstddef>

#define LRALPHA 0.2f

typedef _Float16 half8 __attribute__((ext_vector_type(8)));
typedef float f32x4 __attribute__((ext_vector_type(4)));

// ---------------------------------------------------------------------------
// Kernel 1: Wh = h @ W (8192x512 @ 512x64), writes:
//   whTsw : f16, swizzled MFMA-B layout: [j/32][cp:4][c:16][ks:4][e:8]
//   wh1   : f32 [8192]  (Wh @ a[:64])
//   wh2   : f32 [8192]  (Wh @ a[64:])
// ---------------------------------------------------------------------------
__global__ __launch_bounds__(256) void k1_wh(
    const float* __restrict__ h, const float* __restrict__ W, const float* __restrict__ a,
    _Float16* __restrict__ whTsw, float* __restrict__ wh1, float* __restrict__ wh2)
{
  __shared__ __align__(16) float h_lds[32][34];   // [k][row]
  __shared__ __align__(16) float w_lds[32][64];   // [k][col]
  __shared__ __align__(16) _Float16 whT_l[64][32]; // [col][ilocal]

  const int t = threadIdx.x;
  const int tx = t & 15, ty = t >> 4;
  const int i0 = blockIdx.x * 32;

  const int hrow = t >> 3, hk4 = (t & 7) * 4;
  const int wk = t >> 3, wc = (t & 7) * 8;

  float acc00 = 0, acc01 = 0, acc02 = 0, acc03 = 0;
  float acc10 = 0, acc11 = 0, acc12 = 0, acc13 = 0;

  float4 hv  = *reinterpret_cast<const float4*>(&h[(size_t)(i0 + hrow) * 512 + hk4]);
  float4 wv0 = *reinterpret_cast<const float4*>(&W[(size_t)wk * 64 + wc]);
  float4 wv1 = *reinterpret_cast<const float4*>(&W[(size_t)wk * 64 + wc + 4]);

  for (int k0 = 0; k0 < 512; k0 += 32) {
    h_lds[hk4 + 0][hrow] = hv.x;
    h_lds[hk4 + 1][hrow] = hv.y;
    h_lds[hk4 + 2][hrow] = hv.z;
    h_lds[hk4 + 3][hrow] = hv.w;
    *reinterpret_cast<float4*>(&w_lds[wk][wc])     = wv0;
    *reinterpret_cast<float4*>(&w_lds[wk][wc + 4]) = wv1;
    __syncthreads();
    if (k0 + 32 < 512) {
      hv  = *reinterpret_cast<const float4*>(&h[(size_t)(i0 + hrow) * 512 + k0 + 32 + hk4]);
      wv0 = *reinterpret_cast<const float4*>(&W[(size_t)(k0 + 32 + wk) * 64 + wc]);
      wv1 = *reinterpret_cast<const float4*>(&W[(size_t)(k0 + 32 + wk) * 64 + wc + 4]);
    }
#pragma unroll
    for (int kk = 0; kk < 32; ++kk) {
      float2 av = *reinterpret_cast<const float2*>(&h_lds[kk][ty * 2]);
      float4 bv = *reinterpret_cast<const float4*>(&w_lds[kk][tx * 4]);
      acc00 += av.x * bv.x; acc01 += av.x * bv.y; acc02 += av.x * bv.z; acc03 += av.x * bv.w;
      acc10 += av.y * bv.x; acc11 += av.y * bv.y; acc12 += av.y * bv.z; acc13 += av.y * bv.w;
    }
    __syncthreads();
  }

  const float a10 = a[tx * 4 + 0], a11 = a[tx * 4 + 1], a12 = a[tx * 4 + 2], a13 = a[tx * 4 + 3];
  const float a20 = a[64 + tx * 4 + 0], a21 = a[64 + tx * 4 + 1], a22 = a[64 + tx * 4 + 2], a23 = a[64 + tx * 4 + 3];
  float s1_0 = acc00 * a10 + acc01 * a11 + acc02 * a12 + acc03 * a13;
  float s1_1 = acc10 * a10 + acc11 * a11 + acc12 * a12 + acc13 * a13;
  float s2_0 = acc00 * a20 + acc01 * a21 + acc02 * a22 + acc03 * a23;
  float s2_1 = acc10 * a20 + acc11 * a21 + acc12 * a22 + acc13 * a23;
#pragma unroll
  for (int m = 1; m < 16; m <<= 1) {
    s1_0 += __shfl_xor(s1_0, m); s1_1 += __shfl_xor(s1_1, m);
    s2_0 += __shfl_xor(s2_0, m); s2_1 += __shfl_xor(s2_1, m);
  }
  if (tx == 0) {
    wh1[i0 + ty * 2 + 0] = s1_0; wh1[i0 + ty * 2 + 1] = s1_1;
    wh2[i0 + ty * 2 + 0] = s2_0; wh2[i0 + ty * 2 + 1] = s2_1;
  }

  whT_l[tx * 4 + 0][ty * 2 + 0] = (_Float16)acc00;
  whT_l[tx * 4 + 1][ty * 2 + 0] = (_Float16)acc01;
  whT_l[tx * 4 + 2][ty * 2 + 0] = (_Float16)acc02;
  whT_l[tx * 4 + 3][ty * 2 + 0] = (_Float16)acc03;
  whT_l[tx * 4 + 0][ty * 2 + 1] = (_Float16)acc10;
  whT_l[tx * 4 + 1][ty * 2 + 1] = (_Float16)acc11;
  whT_l[tx * 4 + 2][ty * 2 + 1] = (_Float16)acc12;
  whT_l[tx * 4 + 3][ty * 2 + 1] = (_Float16)acc13;
  __syncthreads();
  {
    const int cp = t >> 6, cc = (t >> 2) & 15, ks = t & 3;
    half8 v = *reinterpret_cast<const half8*>(&whT_l[cp * 16 + cc][ks * 8]);
    *reinterpret_cast<half8*>(&whTsw[(size_t)(i0 >> 5) * 2048 + cp * 512 + (cc * 4 + ks) * 8]) = v;
  }
}

// ---------------------------------------------------------------------------
// Kernel 1b: G = max(wh2)
// ---------------------------------------------------------------------------
__global__ __launch_bounds__(256) void k1b_max(const float* __restrict__ wh2,
                                               float* __restrict__ G)
{
  const int t = threadIdx.x;
  float m = -1e30f;
  for (int i = t; i < 8192; i += 256) m = fmaxf(m, wh2[i]);
#pragma unroll
  for (int mask = 32; mask >= 1; mask >>= 1) m = fmaxf(m, __shfl_xor(m, mask));
  __shared__ float wm[4];
  if ((t & 63) == 0) wm[t >> 6] = m;
  __syncthreads();
  if (t == 0) G[0] = fmaxf(fmaxf(wm[0], wm[1]), fmaxf(wm[2], wm[3]));
}

// ---------------------------------------------------------------------------
// Kernel 2s: score pass — streams adj ONCE (coalesced), p = masked
// exp(lrelu(w1+w2) - mh), writes P as **f16** in MFMA-A-fragment layout
// P[tile:512][jb:256][c:16][ks:4][e:8] (128 MB), and per-(stripe,row) denom
// partials Dpart[stripe:8][row:8192] from the f32 ps chain (v4's proven path).
// HBM-bound: 256 MB read + 132 MB write; VALU demand ~9 us (hidden).
// ---------------------------------------------------------------------------
__global__ __launch_bounds__(256) void k2s_score(
    const int* __restrict__ adj, const float* __restrict__ wh1,
    const float* __restrict__ wh2, const float* __restrict__ Gp,
    _Float16* __restrict__ P, float* __restrict__ Dpart)
{
  const int t = threadIdx.x;
  const int lane = t & 63;
  const int w = t >> 6;
  const int g = blockIdx.x * 4 + w;       // 0..4095
  const int tile = g >> 3;                // 0..511
  const int stripe = g & 7;               // 0..7
  const int c = lane & 15, ks = lane >> 4;
  const int row = tile * 16 + c;

  const float Gv = Gp[0];
  const float w1r = wh1[row];
  const float mx = w1r + Gv;
  const float mh = fmaxf(mx, LRALPHA * mx);   // >= all scores of this row (lrelu monotone)

  const int*   ap = adj + (size_t)row * 8192 + stripe * 1024 + ks * 8;
  const float* wp = wh2 + stripe * 1024 + ks * 8;
  _Float16* pp = P + (size_t)(tile * 256 + stripe * 32) * 512 + (c * 4 + ks) * 8;

  float ps = 0.f;

  int4 Aa0, Aa1, Ba0, Ba1;
  float4 Aw0, Aw1, Bw0, Bw1;

#define LOADSET(Q, CI) do {                                                     \
    Q##a0 = *reinterpret_cast<const int4*>(ap + (CI) * 32);                     \
    Q##a1 = *reinterpret_cast<const int4*>(ap + (CI) * 32 + 4);                 \
    Q##w0 = *reinterpret_cast<const float4*>(wp + (CI) * 32);                   \
    Q##w1 = *reinterpret_cast<const float4*>(wp + (CI) * 32 + 4); } while (0)

#define SCORE(AV, WV, E) {                                                      \
    float s_ = w1r + (WV);                                                      \
    s_ = fmaxf(s_, LRALPHA * s_);                                               \
    float p_ = ((AV) > 0) ? __expf(s_ - mh) : 0.f;                              \
    ps += p_; pv[E] = (_Float16)p_; }

#define BODY(Q, CI, NEXTCI) do {                                                \
    const int4 a0 = Q##a0, a1 = Q##a1;                                          \
    const float4 q0 = Q##w0, q1 = Q##w1;                                        \
    if ((NEXTCI) < 32) LOADSET(Q, NEXTCI);                                      \
    half8 pv;                                                                   \
    SCORE(a0.x, q0.x, 0) SCORE(a0.y, q0.y, 1)                                   \
    SCORE(a0.z, q0.z, 2) SCORE(a0.w, q0.w, 3)                                   \
    SCORE(a1.x, q1.x, 4) SCORE(a1.y, q1.y, 5)                                   \
    SCORE(a1.z, q1.z, 6) SCORE(a1.w, q1.w, 7)                                   \
    *reinterpret_cast<half8*>(pp + (size_t)(CI) * 512) = pv; } while (0)

  LOADSET(A, 0);
  LOADSET(B, 1);
  for (int ci = 0; ci < 32; ci += 2) {
    BODY(A, ci, ci + 2);
    BODY(B, ci + 1, ci + 3);
  }
#undef BODY
#undef SCORE
#undef LOADSET

  // denom partial for this (stripe,row): reduce across the 4 k-subgroups
  float r = ps;
  r += __shfl_xor(r, 16);
  r += __shfl_xor(r, 32);
  if (ks == 0) Dpart[(size_t)stripe * 8192 + row] = r;
}

// ---------------------------------------------------------------------------
// Kernel 3: PV stream-GEMM. 256 blocks x 512 thr; block = 32 rows (2 tiles
// sharing one B-frag stream -> whTsw L2 traffic halved to 256 MB), 8-way
// split-K (wave w: jb in [w*32,+32)). Per body: 2 f16 A-frags (16B each,
// dense stream), 4 B-frags, 8 MFMAs. LDS split-K combine, Dpart sum,
// divide, ELU, store. Near-zero per-element VALU -> pure 128 MB P stream.
// ---------------------------------------------------------------------------
__global__ __launch_bounds__(512) void k3_pv(
    const _Float16* __restrict__ P, const _Float16* __restrict__ whTsw,
    const float* __restrict__ Dpart, float* __restrict__ out)
{
  __shared__ __align__(16) float Osm[8][32][64];  // 64 KB

  const int t = threadIdx.x;
  const int lane = t & 63;
  const int w = t >> 6;
  const int c = lane & 15, ks = lane >> 4;
  const int tile0 = blockIdx.x * 2;
  const int row0 = tile0 * 16;

  const _Float16* pp0 = P + (size_t)(tile0 * 256 + w * 32) * 512 + (c * 4 + ks) * 8;
  const _Float16* pp1 = pp0 + 256 * 512;
  const _Float16* bp  = whTsw + (size_t)(w * 32) * 2048 + (c * 4 + ks) * 8;

  f32x4 a00 = {0.f,0.f,0.f,0.f}, a01 = {0.f,0.f,0.f,0.f};
  f32x4 a02 = {0.f,0.f,0.f,0.f}, a03 = {0.f,0.f,0.f,0.f};
  f32x4 a10 = {0.f,0.f,0.f,0.f}, a11 = {0.f,0.f,0.f,0.f};
  f32x4 a12 = {0.f,0.f,0.f,0.f}, a13 = {0.f,0.f,0.f,0.f};

  half8 Aa, Az, Ab0, Ab1, Ab2, Ab3;
  half8 Ba, Bz, Bb0, Bb1, Bb2, Bb3;

#define LOADSET(Q, CI) do {                                                     \
    Q##a  = *reinterpret_cast<const half8*>(pp0 + (size_t)(CI) * 512);          \
    Q##z  = *reinterpret_cast<const half8*>(pp1 + (size_t)(CI) * 512);          \
    Q##b0 = *reinterpret_cast<const half8*>(bp + (size_t)(CI) * 2048);          \
    Q##b1 = *reinterpret_cast<const half8*>(bp + (size_t)(CI) * 2048 + 512);    \
    Q##b2 = *reinterpret_cast<const half8*>(bp + (size_t)(CI) * 2048 + 1024);   \
    Q##b3 = *reinterpret_cast<const half8*>(bp + (size_t)(CI) * 2048 + 1536); } while (0)

#define BODY(Q, NEXTCI) do {                                                    \
    const half8 fa = Q##a, fz = Q##z;                                           \
    const half8 cb0 = Q##b0, cb1 = Q##b1, cb2 = Q##b2, cb3 = Q##b3;             \
    if ((NEXTCI) < 32) LOADSET(Q, NEXTCI);                                      \
    a00 = __builtin_amdgcn_mfma_f32_16x16x32_f16(fa, cb0, a00, 0, 0, 0);        \
    a01 = __builtin_amdgcn_mfma_f32_16x16x32_f16(fa, cb1, a01, 0, 0, 0);        \
    a02 = __builtin_amdgcn_mfma_f32_16x16x32_f16(fa, cb2, a02, 0, 0, 0);        \
    a03 = __builtin_amdgcn_mfma_f32_16x16x32_f16(fa, cb3, a03, 0, 0, 0);        \
    a10 = __builtin_amdgcn_mfma_f32_16x16x32_f16(fz, cb0, a10, 0, 0, 0);        \
    a11 = __builtin_amdgcn_mfma_f32_16x16x32_f16(fz, cb1, a11, 0, 0, 0);        \
    a12 = __builtin_amdgcn_mfma_f32_16x16x32_f16(fz, cb2, a12, 0, 0, 0);        \
    a13 = __builtin_amdgcn_mfma_f32_16x16x32_f16(fz, cb3, a13, 0, 0, 0);        \
  } while (0)

  LOADSET(A, 0);
  LOADSET(B, 1);
  for (int ci = 0; ci < 32; ci += 2) {
    BODY(A, ci + 2);
    BODY(B, ci + 3);
  }
#undef BODY
#undef LOADSET

#pragma unroll
  for (int q = 0; q < 4; ++q) {
    Osm[w][ks * 4 + q][ 0 + c] = a00[q];
    Osm[w][ks * 4 + q][16 + c] = a01[q];
    Osm[w][ks * 4 + q][32 + c] = a02[q];
    Osm[w][ks * 4 + q][48 + c] = a03[q];
    Osm[w][16 + ks * 4 + q][ 0 + c] = a10[q];
    Osm[w][16 + ks * 4 + q][16 + c] = a11[q];
    Osm[w][16 + ks * 4 + q][32 + c] = a12[q];
    Osm[w][16 + ks * 4 + q][48 + c] = a13[q];
  }
  __syncthreads();

  {
    const int row = t >> 4, c4 = (t & 15) * 4;
    float d = 0.f;
#pragma unroll
    for (int s = 0; s < 8; ++s) d += Dpart[(size_t)s * 8192 + row0 + row];
    const float inv = 1.0f / d;
    float sx = 0.f, sy = 0.f, sz = 0.f, sw = 0.f;
#pragma unroll
    for (int ww = 0; ww < 8; ++ww) {
      float4 v = *reinterpret_cast<const float4*>(&Osm[ww][row][c4]);
      sx += v.x; sy += v.y; sz += v.z; sw += v.w;
    }
    float4 o;
    o.x = sx * inv; o.y = sy * inv; o.z = sz * inv; o.w = sw * inv;
    o.x = o.x > 0.f ? o.x : __expf(o.x) - 1.f;
    o.y = o.y > 0.f ? o.y : __expf(o.y) - 1.f;
    o.z = o.z > 0.f ? o.z : __expf(o.z) - 1.f;
    o.w = o.w > 0.f ? o.w : __expf(o.w) - 1.f;
    *reinterpret_cast<float4*>(&out[(size_t)(row0 + row) * 64 + c4]) = o;
  }
}

// ---------------------------------------------------------------------------
extern "C" void kernel_launch(void* const* d_in, const int* in_sizes, int n_in,
                              void* d_out, int out_size, void* d_ws, size_t ws_size,
                              hipStream_t stream) {
  const float* h   = (const float*)d_in[0];
  const int*   adj = (const int*)d_in[1];
  const float* W   = (const float*)d_in[2];
  const float* a   = (const float*)d_in[3];
  float* out = (float*)d_out;

  char* ws = (char*)d_ws;
  _Float16* whTsw = (_Float16*)ws;                         // [0, 1MB)
  float* wh1   = (float*)(ws + 0x100000);                  // 32 KB
  float* wh2   = (float*)(ws + 0x108000);                  // 32 KB
  float* G     = (float*)(ws + 0x110000);                  // 4 B
  float* Dpart = (float*)(ws + 0x118000);                  // 8*8192*4 = 256 KB
  _Float16* P  = (_Float16*)(ws + 0x200000);               // 128 MB f16 scores

  k1_wh<<<dim3(256), dim3(256), 0, stream>>>(h, W, a, whTsw, wh1, wh2);
  k1b_max<<<dim3(1), dim3(256), 0, stream>>>(wh2, G);
  k2s_score<<<dim3(1024), dim3(256), 0, stream>>>(adj, wh1, wh2, G, P, Dpart);
  k3_pv<<<dim3(256), dim3(512), 0, stream>>>(P, whTsw, Dpart, out);
}